// Round 6
// baseline (55.701 us; speedup 1.0000x reference)
//
#include <hip/hip_runtime.h>
#include <cfloat>

#define BLOCK 256
#define AU 16        // cloud-A points per thread (registers)
#define TS 256       // cloud-B points staged per LDS tile
#define KSPLIT 64    // split of the B dimension for grid parallelism
#define RBLOCK 256

typedef float f2 __attribute__((ext_vector_type(2)));

// Both directions in one launch (blockIdx.z selects). For each point a in A,
// minimize f(b) = 0.5|b|^2 - a.b over B[slice]; d = 2*f_min + |a|^2.
// B staged in LDS as point-PAIRS: sxy = {x0,x1,y0,y1}, szh = {z0,z1,h0,h1}.
// Inner loop per 2 B-points per a: 3 v_pk_fma_f32 + 1 v_min3 -> 2 instr/pair.
__global__ __launch_bounds__(BLOCK, 2) void chamfer_min_kernel(
    const float* __restrict__ pc1, int N,
    const float* __restrict__ pc2, int M,
    float* __restrict__ P1, float* __restrict__ P2)
{
    __shared__ float sxy[TS * 2];  // pair p: {x(2p), x(2p+1), y(2p), y(2p+1)}
    __shared__ float szh[TS * 2];  // pair p: {z(2p), z(2p+1), h(2p), h(2p+1)}
    const int tid = threadIdx.x;

    const float* A; const float* B; float* P; int An, Bn;
    if (blockIdx.z == 0) { A = pc1; An = N; B = pc2; Bn = M; P = P1; }
    else                 { A = pc2; An = M; B = pc1; Bn = N; P = P2; }

    const int abase = blockIdx.x * (BLOCK * AU) + tid;
    const int mlen = (Bn + KSPLIT - 1) / KSPLIT;
    const int m0 = blockIdx.y * mlen;
    const int m1 = min(m0 + mlen, Bn);

    f2 nax2[AU], nay2[AU], naz2[AU];
    #pragma unroll
    for (int u = 0; u < AU; ++u) {
        const int ai = abase + u * BLOCK;
        float x = 0.f, y = 0.f, z = 0.f;
        if (ai < An) {
            x = A[(size_t)ai * 3 + 0];
            y = A[(size_t)ai * 3 + 1];
            z = A[(size_t)ai * 3 + 2];
        }
        nax2[u] = (f2){-x, -x};
        nay2[u] = (f2){-y, -y};
        naz2[u] = (f2){-z, -z};
    }

    float mm[AU];
    #pragma unroll
    for (int u = 0; u < AU; ++u) mm[u] = FLT_MAX;

    for (int t0 = m0; t0 < m1; t0 += TS) {
        const int tcount = min(TS, m1 - t0);
        const int padded = (tcount + 1) & ~1;

        // stage (duplicate last point into odd pad slot)
        for (int j = tid; j < padded; j += BLOCK) {
            const int srcj = min(j, tcount - 1);
            const size_t s = (size_t)(t0 + srcj) * 3;
            float bx = B[s + 0], by = B[s + 1], bz = B[s + 2];
            float h = 0.5f * fmaf(bx, bx, fmaf(by, by, bz * bz));
            const int p = j >> 1, hf = j & 1;
            sxy[p * 4 + 0 + hf] = bx;
            sxy[p * 4 + 2 + hf] = by;
            szh[p * 4 + 0 + hf] = bz;
            szh[p * 4 + 2 + hf] = h;
        }
        __syncthreads();

        const int npair = padded >> 1;
        const float4* __restrict__ qxyp = (const float4*)sxy;
        const float4* __restrict__ qzhp = (const float4*)szh;
        #pragma unroll 2
        for (int p = 0; p < npair; ++p) {
            float4 qxy = qxyp[p];
            float4 qzh = qzhp[p];
            f2 x2; x2.x = qxy.x; x2.y = qxy.y;
            f2 y2; y2.x = qxy.z; y2.y = qxy.w;
            f2 z2; z2.x = qzh.x; z2.y = qzh.y;
            f2 h2; h2.x = qzh.z; h2.y = qzh.w;
            #pragma unroll
            for (int u = 0; u < AU; ++u) {
                f2 acc;
                asm("v_pk_fma_f32 %0, %1, %2, %3"
                    : "=v"(acc) : "v"(naz2[u]), "v"(z2), "v"(h2));
                asm("v_pk_fma_f32 %0, %1, %2, %0"
                    : "+v"(acc) : "v"(nay2[u]), "v"(y2));
                asm("v_pk_fma_f32 %0, %1, %2, %0"
                    : "+v"(acc) : "v"(nax2[u]), "v"(x2));
                mm[u] = fminf(fminf(mm[u], acc.x), acc.y);  // v_min3
            }
        }
        __syncthreads();
    }

    #pragma unroll
    for (int u = 0; u < AU; ++u) {
        const int ai = abase + u * BLOCK;
        if (ai < An) {
            const float x = nax2[u].x, y = nay2[u].x, z = naz2[u].x;
            const float a2 = fmaf(x, x, fmaf(y, y, z * z));
            float d = fmaf(2.0f, mm[u], a2);
            P[(size_t)blockIdx.y * An + ai] = fmaxf(d, 0.0f);
        }
    }
}

// Stage 1: one thread per point; min across KSPLIT partials, scaled partial mean.
__global__ __launch_bounds__(RBLOCK) void chamfer_reduce1_kernel(
    const float* __restrict__ P1, int N,
    const float* __restrict__ P2, int M,
    double* __restrict__ bsum)
{
    const int tid = threadIdx.x;
    const int g = blockIdx.x * RBLOCK + tid;
    double s = 0.0;
    const int T = N + M;
    if (g < T) {
        const float* base; int stride, i; double scale;
        if (g < N) { base = P1; stride = N; i = g;     scale = 1.0 / (double)N; }
        else       { base = P2; stride = M; i = g - N; scale = 1.0 / (double)M; }
        float v = FLT_MAX;
        #pragma unroll 16
        for (int k = 0; k < KSPLIT; ++k)
            v = fminf(v, base[(size_t)k * stride + i]);
        s = (double)v * scale;
    }
    for (int off = 32; off > 0; off >>= 1)
        s += __shfl_down(s, off, 64);
    __shared__ double wsum[RBLOCK / 64];
    if ((tid & 63) == 0) wsum[tid >> 6] = s;
    __syncthreads();
    if (tid == 0) {
        double tot = 0.0;
        #pragma unroll
        for (int w = 0; w < RBLOCK / 64; ++w) tot += wsum[w];
        bsum[blockIdx.x] = tot;
    }
}

// Stage 2: single block sums the per-block doubles.
__global__ __launch_bounds__(RBLOCK) void chamfer_reduce2_kernel(
    const double* __restrict__ bsum, int nb, float* __restrict__ out)
{
    const int tid = threadIdx.x;
    double s = 0.0;
    for (int i = tid; i < nb; i += RBLOCK) s += bsum[i];
    for (int off = 32; off > 0; off >>= 1)
        s += __shfl_down(s, off, 64);
    __shared__ double wsum[RBLOCK / 64];
    if ((tid & 63) == 0) wsum[tid >> 6] = s;
    __syncthreads();
    if (tid == 0) {
        double tot = 0.0;
        #pragma unroll
        for (int w = 0; w < RBLOCK / 64; ++w) tot += wsum[w];
        out[0] = (float)tot;
    }
}

extern "C" void kernel_launch(void* const* d_in, const int* in_sizes, int n_in,
                              void* d_out, int out_size, void* d_ws, size_t ws_size,
                              hipStream_t stream) {
    const float* pc1 = (const float*)d_in[0];
    const float* pc2 = (const float*)d_in[1];
    const int N = in_sizes[0] / 3;
    const int M = in_sizes[1] / 3;

    float* P1 = (float*)d_ws;                       // [KSPLIT][N]
    float* P2 = P1 + (size_t)KSPLIT * N;            // [KSPLIT][M]
    double* bsum = (double*)(P2 + (size_t)KSPLIT * M);
    float* out = (float*)d_out;

    const int maxNM = (N > M) ? N : M;
    const int gx = (maxNM + BLOCK * AU - 1) / (BLOCK * AU);
    dim3 grid(gx, KSPLIT, 2);
    chamfer_min_kernel<<<grid, BLOCK, 0, stream>>>(pc1, N, pc2, M, P1, P2);

    const int gr = (N + M + RBLOCK - 1) / RBLOCK;
    chamfer_reduce1_kernel<<<gr, RBLOCK, 0, stream>>>(P1, N, P2, M, bsum);
    chamfer_reduce2_kernel<<<1, RBLOCK, 0, stream>>>(bsum, gr, out);
}

// Round 7
// 54.970 us; speedup vs baseline: 1.0133x; 1.0133x over previous
//
#include <hip/hip_runtime.h>
#include <cfloat>

#define BLOCK 256
#define AU 8         // cloud-A points per thread (registers)
#define TS 256       // cloud-B points staged per LDS tile
#define KSPLIT 64    // split of the B dimension for grid parallelism
#define RBLOCK 256

typedef float f2 __attribute__((ext_vector_type(2)));

// Both directions in one launch (blockIdx.z selects). For each point a in A,
// minimize f(b) = 0.5|b|^2 - a.b over B[slice]; d = 2*f_min + |a|^2.
// B staged in LDS as point-PAIRS: sxy = {x0,x1,y0,y1}, szh = {z0,z1,h0,h1}.
// Inner loop per 2 B-points per a: 3 v_pk_fma_f32 + 1 v_min3 -> 2 instr/pair.
__global__ __launch_bounds__(BLOCK, 4) void chamfer_min_kernel(
    const float* __restrict__ pc1, int N,
    const float* __restrict__ pc2, int M,
    float* __restrict__ P1, float* __restrict__ P2)
{
    __shared__ float sxy[TS * 2];  // pair p: {x(2p), x(2p+1), y(2p), y(2p+1)}
    __shared__ float szh[TS * 2];  // pair p: {z(2p), z(2p+1), h(2p), h(2p+1)}
    const int tid = threadIdx.x;

    const float* A; const float* B; float* P; int An, Bn;
    if (blockIdx.z == 0) { A = pc1; An = N; B = pc2; Bn = M; P = P1; }
    else                 { A = pc2; An = M; B = pc1; Bn = N; P = P2; }

    const int abase = blockIdx.x * (BLOCK * AU) + tid;
    const int mlen = (Bn + KSPLIT - 1) / KSPLIT;
    const int m0 = blockIdx.y * mlen;
    const int m1 = min(m0 + mlen, Bn);

    f2 nax2[AU], nay2[AU], naz2[AU];
    #pragma unroll
    for (int u = 0; u < AU; ++u) {
        const int ai = abase + u * BLOCK;
        float x = 0.f, y = 0.f, z = 0.f;
        if (ai < An) {
            x = A[(size_t)ai * 3 + 0];
            y = A[(size_t)ai * 3 + 1];
            z = A[(size_t)ai * 3 + 2];
        }
        nax2[u] = (f2){-x, -x};
        nay2[u] = (f2){-y, -y};
        naz2[u] = (f2){-z, -z};
    }

    float mm[AU];
    #pragma unroll
    for (int u = 0; u < AU; ++u) mm[u] = FLT_MAX;

    for (int t0 = m0; t0 < m1; t0 += TS) {
        const int tcount = min(TS, m1 - t0);
        const int padded = (tcount + 1) & ~1;

        // stage (duplicate last point into odd pad slot)
        for (int j = tid; j < padded; j += BLOCK) {
            const int srcj = min(j, tcount - 1);
            const size_t s = (size_t)(t0 + srcj) * 3;
            float bx = B[s + 0], by = B[s + 1], bz = B[s + 2];
            float h = 0.5f * fmaf(bx, bx, fmaf(by, by, bz * bz));
            const int p = j >> 1, hf = j & 1;
            sxy[p * 4 + 0 + hf] = bx;
            sxy[p * 4 + 2 + hf] = by;
            szh[p * 4 + 0 + hf] = bz;
            szh[p * 4 + 2 + hf] = h;
        }
        __syncthreads();

        const int npair = padded >> 1;
        const float4* __restrict__ qxyp = (const float4*)sxy;
        const float4* __restrict__ qzhp = (const float4*)szh;
        #pragma unroll 4
        for (int p = 0; p < npair; ++p) {
            float4 qxy = qxyp[p];
            float4 qzh = qzhp[p];
            f2 x2; x2.x = qxy.x; x2.y = qxy.y;
            f2 y2; y2.x = qxy.z; y2.y = qxy.w;
            f2 z2; z2.x = qzh.x; z2.y = qzh.y;
            f2 h2; h2.x = qzh.z; h2.y = qzh.w;
            #pragma unroll
            for (int u = 0; u < AU; ++u) {
                f2 acc;
                asm("v_pk_fma_f32 %0, %1, %2, %3"
                    : "=v"(acc) : "v"(naz2[u]), "v"(z2), "v"(h2));
                asm("v_pk_fma_f32 %0, %1, %2, %0"
                    : "+v"(acc) : "v"(nay2[u]), "v"(y2));
                asm("v_pk_fma_f32 %0, %1, %2, %0"
                    : "+v"(acc) : "v"(nax2[u]), "v"(x2));
                mm[u] = fminf(fminf(mm[u], acc.x), acc.y);  // v_min3
            }
        }
        __syncthreads();
    }

    #pragma unroll
    for (int u = 0; u < AU; ++u) {
        const int ai = abase + u * BLOCK;
        if (ai < An) {
            const float x = nax2[u].x, y = nay2[u].x, z = naz2[u].x;
            const float a2 = fmaf(x, x, fmaf(y, y, z * z));
            float d = fmaf(2.0f, mm[u], a2);
            P[(size_t)blockIdx.y * An + ai] = fmaxf(d, 0.0f);
        }
    }
}

// Stage 1: one thread per point; min across KSPLIT partials, scaled partial mean.
__global__ __launch_bounds__(RBLOCK) void chamfer_reduce1_kernel(
    const float* __restrict__ P1, int N,
    const float* __restrict__ P2, int M,
    double* __restrict__ bsum)
{
    const int tid = threadIdx.x;
    const int g = blockIdx.x * RBLOCK + tid;
    double s = 0.0;
    const int T = N + M;
    if (g < T) {
        const float* base; int stride, i; double scale;
        if (g < N) { base = P1; stride = N; i = g;     scale = 1.0 / (double)N; }
        else       { base = P2; stride = M; i = g - N; scale = 1.0 / (double)M; }
        float v = FLT_MAX;
        #pragma unroll 16
        for (int k = 0; k < KSPLIT; ++k)
            v = fminf(v, base[(size_t)k * stride + i]);
        s = (double)v * scale;
    }
    for (int off = 32; off > 0; off >>= 1)
        s += __shfl_down(s, off, 64);
    __shared__ double wsum[RBLOCK / 64];
    if ((tid & 63) == 0) wsum[tid >> 6] = s;
    __syncthreads();
    if (tid == 0) {
        double tot = 0.0;
        #pragma unroll
        for (int w = 0; w < RBLOCK / 64; ++w) tot += wsum[w];
        bsum[blockIdx.x] = tot;
    }
}

// Stage 2: single block sums the per-block doubles.
__global__ __launch_bounds__(RBLOCK) void chamfer_reduce2_kernel(
    const double* __restrict__ bsum, int nb, float* __restrict__ out)
{
    const int tid = threadIdx.x;
    double s = 0.0;
    for (int i = tid; i < nb; i += RBLOCK) s += bsum[i];
    for (int off = 32; off > 0; off >>= 1)
        s += __shfl_down(s, off, 64);
    __shared__ double wsum[RBLOCK / 64];
    if ((tid & 63) == 0) wsum[tid >> 6] = s;
    __syncthreads();
    if (tid == 0) {
        double tot = 0.0;
        #pragma unroll
        for (int w = 0; w < RBLOCK / 64; ++w) tot += wsum[w];
        out[0] = (float)tot;
    }
}

extern "C" void kernel_launch(void* const* d_in, const int* in_sizes, int n_in,
                              void* d_out, int out_size, void* d_ws, size_t ws_size,
                              hipStream_t stream) {
    const float* pc1 = (const float*)d_in[0];
    const float* pc2 = (const float*)d_in[1];
    const int N = in_sizes[0] / 3;
    const int M = in_sizes[1] / 3;

    float* P1 = (float*)d_ws;                       // [KSPLIT][N]
    float* P2 = P1 + (size_t)KSPLIT * N;            // [KSPLIT][M]
    double* bsum = (double*)(P2 + (size_t)KSPLIT * M);
    float* out = (float*)d_out;

    const int maxNM = (N > M) ? N : M;
    const int gx = (maxNM + BLOCK * AU - 1) / (BLOCK * AU);
    dim3 grid(gx, KSPLIT, 2);
    chamfer_min_kernel<<<grid, BLOCK, 0, stream>>>(pc1, N, pc2, M, P1, P2);

    const int gr = (N + M + RBLOCK - 1) / RBLOCK;
    chamfer_reduce1_kernel<<<gr, RBLOCK, 0, stream>>>(P1, N, P2, M, bsum);
    chamfer_reduce2_kernel<<<1, RBLOCK, 0, stream>>>(bsum, gr, out);
}